// Round 1
// baseline (132.649 us; speedup 1.0000x reference)
//
#include <hip/hip_runtime.h>

// SpatialTransformerNetwork: B=16,C=3,H=W=256 -> out [16,3,100,100]
// 121 Gaussian taps (11x11), bilinear grid_sample, zeros padding, align_corners=False.
//
// Strategy: one WAVE per output pixel; lane l handles taps l and l+64.
// Tap offsets are tiny (~+-2px), so the 64 lanes' gather addresses cluster
// into a handful of cache lines -> cheap address divergence.
// Channels interleaved into [B][H][W][4] float4 (pre-pass) so one dwordx4
// fetches all 3 channels. Butterfly reduce 3 channel sums + raw weight sum,
// divide at the end (== reference's pre-normalized weights).

#define BB 16
#define HWPLANE 65536   // 256*256
#define MOUT 100

__global__ __launch_bounds__(256) void stn_interleave(const float* __restrict__ x,
                                                      float4* __restrict__ xi) {
  int idx = blockIdx.x * 256 + threadIdx.x;   // 0 .. 16*65536-1
  int b = idx >> 16;
  int p = idx & 65535;
  const float* xb = x + (size_t)b * 3 * HWPLANE + p;
  xi[idx] = make_float4(xb[0], xb[HWPLANE], xb[2 * HWPLANE], 0.0f);
}

template <int ILV>
__global__ __launch_bounds__(256) void stn_main(const float* __restrict__ x,
                                                const float4* __restrict__ xi,
                                                const float* __restrict__ theta,
                                                float* __restrict__ out) {
  // 40000 blocks; bijective XCD swizzle (q = 40000/8 = 5000): each XCD gets a
  // contiguous 5000-block chunk == 2 batches -> per-XCD L2 working set ~2MB.
  int bid = blockIdx.x;
  int swz = (bid & 7) * 5000 + (bid >> 3);
  int wave = threadIdx.x >> 6;
  int lane = threadIdx.x & 63;
  int pix = swz * 4 + wave;                 // 0..159999
  int b = pix / 10000;
  int rem = pix - b * 10000;
  int i = rem / 100;                        // output row
  int j = rem - i * 100;                    // output col

  const float* th = theta + b * 6;
  float th00 = th[0], th01 = th[1], th02 = th[2];
  float th10 = th[3], th11 = th[4], th12 = th[5];

  // affine_grid base coords (align_corners=False pixel centers)
  float linj = (j + 0.5f) * 0.02f - 1.0f;
  float lini = (i + 0.5f) * 0.02f - 1.0f;
  // unnormalize: ix = gx*128 + 127.5
  float bix = (th00 * linj + th01 * lini + th02) * 128.0f + 127.5f;
  float biy = (th10 * linj + th11 * lini + th12) * 128.0f + 127.5f;

  float acc0 = 0.f, acc1 = 0.f, acc2 = 0.f, accw = 0.f;

#pragma unroll
  for (int half = 0; half < 2; ++half) {
    int tap = lane + half * 64;
    if (tap < 121) {
      int s = tap / 11;             // dx index (meshgrid 'ij': bx = lin[t//11])
      int t = tap - s * 11;         // dy index
      float dx = (float)(s + 1) * (1.0f / 6.0f) - 1.0f;   // linspace(-1,1,13)[1:-1]
      float dy = (float)(t + 1) * (1.0f / 6.0f) - 1.0f;
      float w = __expf(-8.0f * (dx * dx + dy * dy));      // N_SIGMA^2/2 = 8
      accw += w;
      // grid shift: theta[:, :, 2] += th[:,0]*dx*scale + th[:,1]*dy*scale
      // scale = 1/99; pixel units: *128
      float offx = (th00 * dx + th01 * dy) * (128.0f / 99.0f);
      float offy = (th10 * dx + th11 * dy) * (128.0f / 99.0f);
      float ixf = bix + offx;
      float iyf = biy + offy;
      float ix0f = floorf(ixf), iy0f = floorf(iyf);
      float fx = ixf - ix0f, fy = iyf - iy0f;
      int ix0 = (int)ix0f, iy0 = (int)iy0f;
      int ix1 = ix0 + 1, iy1 = iy0 + 1;
      // zeros padding: per-axis validity folded into weights
      float wx0 = ((unsigned)ix0 < 256u) ? (1.0f - fx) : 0.0f;
      float wx1 = ((unsigned)ix1 < 256u) ? fx : 0.0f;
      float wy0 = ((unsigned)iy0 < 256u) ? (1.0f - fy) : 0.0f;
      float wy1 = ((unsigned)iy1 < 256u) ? fy : 0.0f;
      int x0c = min(max(ix0, 0), 255);
      int x1c = min(max(ix1, 0), 255);
      int y0c = min(max(iy0, 0), 255);
      int y1c = min(max(iy1, 0), 255);
      float w00 = w * wy0 * wx0;
      float w01 = w * wy0 * wx1;
      float w10 = w * wy1 * wx0;
      float w11 = w * wy1 * wx1;
      if (ILV) {
        const float4* xb = xi + (size_t)b * HWPLANE;
        float4 v00 = xb[y0c * 256 + x0c];
        float4 v01 = xb[y0c * 256 + x1c];
        float4 v10 = xb[y1c * 256 + x0c];
        float4 v11 = xb[y1c * 256 + x1c];
        acc0 += w00 * v00.x + w01 * v01.x + w10 * v10.x + w11 * v11.x;
        acc1 += w00 * v00.y + w01 * v01.y + w10 * v10.y + w11 * v11.y;
        acc2 += w00 * v00.z + w01 * v01.z + w10 * v10.z + w11 * v11.z;
      } else {
        const float* xb0 = x + (size_t)b * 3 * HWPLANE;
        int a00 = y0c * 256 + x0c, a01 = y0c * 256 + x1c;
        int a10 = y1c * 256 + x0c, a11 = y1c * 256 + x1c;
        acc0 += w00 * xb0[a00] + w01 * xb0[a01] + w10 * xb0[a10] + w11 * xb0[a11];
        const float* xb1 = xb0 + HWPLANE;
        acc1 += w00 * xb1[a00] + w01 * xb1[a01] + w10 * xb1[a10] + w11 * xb1[a11];
        const float* xb2 = xb0 + 2 * HWPLANE;
        acc2 += w00 * xb2[a00] + w01 * xb2[a01] + w10 * xb2[a10] + w11 * xb2[a11];
      }
    }
  }

  // 64-lane butterfly reduction (all lanes end with full sums)
#pragma unroll
  for (int m = 1; m < 64; m <<= 1) {
    acc0 += __shfl_xor(acc0, m, 64);
    acc1 += __shfl_xor(acc1, m, 64);
    acc2 += __shfl_xor(acc2, m, 64);
    accw += __shfl_xor(accw, m, 64);
  }

  if (lane == 0) {
    float inv = 1.0f / accw;   // accw == sum of all 121 raw Gaussian weights
    float* ob = out + (size_t)b * 30000 + i * 100 + j;
    ob[0] = acc0 * inv;
    ob[10000] = acc1 * inv;
    ob[20000] = acc2 * inv;
  }
}

extern "C" void kernel_launch(void* const* d_in, const int* in_sizes, int n_in,
                              void* d_out, int out_size, void* d_ws, size_t ws_size,
                              hipStream_t stream) {
  const float* x = (const float*)d_in[0];      // [16,3,256,256] f32
  const float* theta = (const float*)d_in[1];  // [16,2,3] f32
  float* out = (float*)d_out;                  // [16,3,100,100] f32

  const size_t need = (size_t)BB * HWPLANE * sizeof(float4);  // 16 MiB
  if (ws_size >= need) {
    float4* xi = (float4*)d_ws;
    stn_interleave<<<(BB * HWPLANE) / 256, 256, 0, stream>>>(x, xi);
    stn_main<1><<<40000, 256, 0, stream>>>(x, xi, theta, out);
  } else {
    stn_main<0><<<40000, 256, 0, stream>>>(x, nullptr, theta, out);
  }
}

// Round 3
// 123.211 us; speedup vs baseline: 1.0766x; 1.0766x over previous
//
#include <hip/hip_runtime.h>

// SpatialTransformerNetwork: B=16,C=3,H=W=256 -> out [16,3,100,100]
// 121 Gaussian taps (11x11), bilinear grid_sample, zeros padding, align_corners=False.
//
// R2 strategy (VALU-issue-bound per R1 counters: VALUBusy 91%, HBM 0.8%):
//  - one WAVE per output pixel, lane l handles taps l and l+64 (gather locality:
//    64 lanes' addresses cluster into ~6 cache lines).
//  - per-batch tap LUT (offx, offy, w_normalized) precomputed -> kills exp/affine
//    shift/normalization per tap.
//  - zero-border padded interleaved image [16][258][258]x(float4 of 3 channels):
//    OOB corners clamp into the zero border -> no validity cmp/cndmask per tap.
//  - readfirstlane on wave id -> wave-uniform setup scalarized, saddr gathers.

#define BB 16
#define HWP 65536     // 256*256
#define SP 258        // padded dim
#define SPP (SP * SP) // 66564 per-batch padded plane (float4 elems)

// ---- pass 1: padded channel-interleave: x[B,3,256,256] -> xi[B,258,258] float4 ----
__global__ __launch_bounds__(256) void stn_pad(const float* __restrict__ x,
                                               float4* __restrict__ xi) {
  int idx = blockIdx.x * 256 + threadIdx.x;
  int b = idx / SPP;
  if (b >= BB) return;
  int p = idx - b * SPP;
  int py = p / SP, px = p - py * SP;
  float4 v = make_float4(0.f, 0.f, 0.f, 0.f);
  if (py >= 1 && py <= 256 && px >= 1 && px <= 256) {
    const float* xb = x + (size_t)b * 3 * HWP + (py - 1) * 256 + (px - 1);
    v = make_float4(xb[0], xb[HWP], xb[2 * HWP], 0.f);
  }
  xi[idx] = v;
}

// ---- pass 2: per-batch tap table: (offx_px, offy_px, w/sum(w), 0) x 128 ----
__global__ __launch_bounds__(128) void stn_tab(const float* __restrict__ theta,
                                               float4* __restrict__ tab) {
  __shared__ float sw[128];
  int b = blockIdx.x, t = threadIdx.x;
  int s = t / 11, u = t - s * 11;                      // bx = lin[t/11], by = lin[t%11]
  float dx = (float)(s + 1) * (1.0f / 6.0f) - 1.0f;    // linspace(-1,1,13)[1:-1]
  float dy = (float)(u + 1) * (1.0f / 6.0f) - 1.0f;
  float w = (t < 121) ? expf(-8.0f * (dx * dx + dy * dy)) : 0.0f;  // N_SIGMA^2/2 = 8
  sw[t] = w;
  __syncthreads();
  for (int m = 64; m > 0; m >>= 1) {
    if (t < m) sw[t] += sw[t + m];
    __syncthreads();
  }
  float inv = 1.0f / sw[0];
  const float* th = theta + b * 6;
  // pixel-units shift: ((th00*dx + th01*dy) * scale) * 128, scale = 1/99
  float offx = (th[0] * dx + th[1] * dy) * (128.0f / 99.0f);
  float offy = (th[3] * dx + th[4] * dy) * (128.0f / 99.0f);
  if (t >= 121) { offx = 0.f; offy = 0.f; w = 0.f; }
  tab[b * 128 + t] = make_float4(offx, offy, w * inv, 0.f);
}

// ---- pass 3: main — 1 wave per output pixel, lane-per-tap ----
__global__ __launch_bounds__(256) void stn_main(const float4* __restrict__ xi,
                                                const float4* __restrict__ tab,
                                                const float* __restrict__ theta,
                                                float* __restrict__ out) {
  // bijective XCD swizzle over 40000 blocks (q=5000): per-XCD L2 set ~2 batches.
  int bid = blockIdx.x;
  int swz = (bid & 7) * 5000 + (bid >> 3);
  int wave = __builtin_amdgcn_readfirstlane(threadIdx.x >> 6);  // wave-uniform
  int lane = threadIdx.x & 63;
  int pix = swz * 4 + wave;              // 0..159999 (uniform -> SALU decode)
  int b = pix / 10000;
  int rem = pix - b * 10000;
  int i = rem / 100;
  int j = rem - i * 100;

  const float* th = theta + b * 6;
  float th00 = th[0], th01 = th[1], th02 = th[2];
  float th10 = th[3], th11 = th[4], th12 = th[5];

  // affine_grid base coords (align_corners=False), unnormalized to pixel units
  float linj = (j + 0.5f) * 0.02f - 1.0f;
  float lini = (i + 0.5f) * 0.02f - 1.0f;
  float bix = (th00 * linj + th01 * lini + th02) * 128.0f + 127.5f;
  float biy = (th10 * linj + th11 * lini + th12) * 128.0f + 127.5f;

  // this lane's two taps (coalesced float4 loads)
  const float4* tb = tab + b * 128 + lane;
  float4 t0 = tb[0];
  float4 t1 = tb[64];

  const float4* xb = xi + (size_t)b * SPP;

  float acc0 = 0.f, acc1 = 0.f, acc2 = 0.f;

#pragma unroll
  for (int h = 0; h < 2; ++h) {
    float4 tv = h ? t1 : t0;
    float ixf = bix + tv.x;
    float iyf = biy + tv.y;
    float ix0f = floorf(ixf), iy0f = floorf(iyf);
    float fx = ixf - ix0f, fy = iyf - iy0f;
    int xi0 = (int)ix0f, yi0 = (int)iy0f;
    // clamp into padded coords [0,257]; OOB corners land on the zero border
    int x0p = min(max(xi0 + 1, 0), 257);
    int x1p = min(max(xi0 + 2, 0), 257);
    int y0p = min(max(yi0 + 1, 0), 257);
    int y1p = min(max(yi0 + 2, 0), 257);
    float wn = tv.z;
    float u = wn - wn * fx;   // wn*(1-fx)
    float v = wn * fx;
    float w00 = u - u * fy, w10 = u * fy;
    float w01 = v - v * fy, w11 = v * fy;
    int a0 = y0p * SP, a1 = y1p * SP;
    float4 v00 = xb[a0 + x0p];
    float4 v01 = xb[a0 + x1p];
    float4 v10 = xb[a1 + x0p];
    float4 v11 = xb[a1 + x1p];
    acc0 += w00 * v00.x + w01 * v01.x + w10 * v10.x + w11 * v11.x;
    acc1 += w00 * v00.y + w01 * v01.y + w10 * v10.y + w11 * v11.y;
    acc2 += w00 * v00.z + w01 * v01.z + w10 * v10.z + w11 * v11.z;
  }

  // 64-lane butterfly reduction (3 accumulators; normalization already in LUT)
#pragma unroll
  for (int m = 1; m < 64; m <<= 1) {
    acc0 += __shfl_xor(acc0, m, 64);
    acc1 += __shfl_xor(acc1, m, 64);
    acc2 += __shfl_xor(acc2, m, 64);
  }

  if (lane == 0) {
    float* ob = out + (size_t)b * 30000 + i * 100 + j;
    ob[0] = acc0;
    ob[10000] = acc1;
    ob[20000] = acc2;
  }
}

// ---- fallback (ws too small): self-contained, bounds-checked, reads x directly ----
__global__ __launch_bounds__(256) void stn_main_fb(const float* __restrict__ x,
                                                   const float* __restrict__ theta,
                                                   float* __restrict__ out) {
  int bid = blockIdx.x;
  int swz = (bid & 7) * 5000 + (bid >> 3);
  int wave = threadIdx.x >> 6;
  int lane = threadIdx.x & 63;
  int pix = swz * 4 + wave;
  int b = pix / 10000;
  int rem = pix - b * 10000;
  int i = rem / 100;
  int j = rem - i * 100;

  const float* th = theta + b * 6;
  float th00 = th[0], th01 = th[1], th02 = th[2];
  float th10 = th[3], th11 = th[4], th12 = th[5];

  float linj = (j + 0.5f) * 0.02f - 1.0f;
  float lini = (i + 0.5f) * 0.02f - 1.0f;
  float bix = (th00 * linj + th01 * lini + th02) * 128.0f + 127.5f;
  float biy = (th10 * linj + th11 * lini + th12) * 128.0f + 127.5f;

  float acc0 = 0.f, acc1 = 0.f, acc2 = 0.f, accw = 0.f;

#pragma unroll
  for (int half = 0; half < 2; ++half) {
    int tap = lane + half * 64;
    if (tap < 121) {
      int s = tap / 11;
      int t = tap - s * 11;
      float dx = (float)(s + 1) * (1.0f / 6.0f) - 1.0f;
      float dy = (float)(t + 1) * (1.0f / 6.0f) - 1.0f;
      float w = __expf(-8.0f * (dx * dx + dy * dy));
      accw += w;
      float offx = (th00 * dx + th01 * dy) * (128.0f / 99.0f);
      float offy = (th10 * dx + th11 * dy) * (128.0f / 99.0f);
      float ixf = bix + offx;
      float iyf = biy + offy;
      float ix0f = floorf(ixf), iy0f = floorf(iyf);
      float fx = ixf - ix0f, fy = iyf - iy0f;
      int ix0 = (int)ix0f, iy0 = (int)iy0f;
      int ix1 = ix0 + 1, iy1 = iy0 + 1;
      float wx0 = ((unsigned)ix0 < 256u) ? (1.0f - fx) : 0.0f;
      float wx1 = ((unsigned)ix1 < 256u) ? fx : 0.0f;
      float wy0 = ((unsigned)iy0 < 256u) ? (1.0f - fy) : 0.0f;
      float wy1 = ((unsigned)iy1 < 256u) ? fy : 0.0f;
      int x0c = min(max(ix0, 0), 255);
      int x1c = min(max(ix1, 0), 255);
      int y0c = min(max(iy0, 0), 255);
      int y1c = min(max(iy1, 0), 255);
      float w00 = w * wy0 * wx0;
      float w01 = w * wy0 * wx1;
      float w10 = w * wy1 * wx0;
      float w11 = w * wy1 * wx1;
      const float* xb0 = x + (size_t)b * 3 * HWP;
      int a00 = y0c * 256 + x0c, a01 = y0c * 256 + x1c;
      int a10 = y1c * 256 + x0c, a11 = y1c * 256 + x1c;
      acc0 += w00 * xb0[a00] + w01 * xb0[a01] + w10 * xb0[a10] + w11 * xb0[a11];
      const float* xb1 = xb0 + HWP;
      acc1 += w00 * xb1[a00] + w01 * xb1[a01] + w10 * xb1[a10] + w11 * xb1[a11];
      const float* xb2 = xb0 + 2 * HWP;
      acc2 += w00 * xb2[a00] + w01 * xb2[a01] + w10 * xb2[a10] + w11 * xb2[a11];
    }
  }

#pragma unroll
  for (int m = 1; m < 64; m <<= 1) {
    acc0 += __shfl_xor(acc0, m, 64);
    acc1 += __shfl_xor(acc1, m, 64);
    acc2 += __shfl_xor(acc2, m, 64);
    accw += __shfl_xor(accw, m, 64);
  }

  if (lane == 0) {
    float inv = 1.0f / accw;
    float* ob = out + (size_t)b * 30000 + i * 100 + j;
    ob[0] = acc0 * inv;
    ob[10000] = acc1 * inv;
    ob[20000] = acc2 * inv;
  }
}

extern "C" void kernel_launch(void* const* d_in, const int* in_sizes, int n_in,
                              void* d_out, int out_size, void* d_ws, size_t ws_size,
                              hipStream_t stream) {
  const float* x = (const float*)d_in[0];      // [16,3,256,256] f32
  const float* theta = (const float*)d_in[1];  // [16,2,3] f32
  float* out = (float*)d_out;                  // [16,3,100,100] f32

  const size_t img_bytes = (size_t)BB * SPP * sizeof(float4);   // 17,040,384
  const size_t tab_bytes = (size_t)BB * 128 * sizeof(float4);   // 32,768
  if (ws_size >= img_bytes + tab_bytes) {
    float4* xi = (float4*)d_ws;
    float4* tab = (float4*)((char*)d_ws + img_bytes);
    stn_pad<<<(BB * SPP + 255) / 256, 256, 0, stream>>>(x, xi);
    stn_tab<<<BB, 128, 0, stream>>>(theta, tab);
    stn_main<<<40000, 256, 0, stream>>>(xi, tab, theta, out);
  } else {
    stn_main_fb<<<40000, 256, 0, stream>>>(x, theta, out);
  }
}

// Round 4
// 121.510 us; speedup vs baseline: 1.0917x; 1.0140x over previous
//
#include <hip/hip_runtime.h>

// SpatialTransformerNetwork: B=16,C=3,H=W=256 -> out [16,3,100,100]
// 121 Gaussian taps (11x11), bilinear grid_sample, zeros padding, align_corners=False.
//
// R4: 4 pixels per wave, 16 lanes per pixel (tap = sub + 16k, k=0..7).
//  - reduction: 4-level butterfly amortized over 4 px (was 6-level per px)
//  - 2-wide zero border (260x260 float4): ONE med3 clamp per axis; x1=x0+1,
//    y1 row = +4160B; +1-column folds into load immediate offset.
//  - taps 121..127 carry weight 0 in LUT -> all 8 rounds branchless.
//  - all 8 taps preloaded -> inner loop pure FMA+gather, rounds independent.

#define BB 16
#define HWP 65536      // 256*256
#define SP 260         // padded dim (2 left/top zeros, 2 right/bottom zeros)
#define SPP (SP * SP)  // 67600 float4 per batch

// ---- pass 1: padded channel-interleave: x[B,3,256,256] -> xi[B,260,260] float4 ----
__global__ __launch_bounds__(256) void stn_pad(const float* __restrict__ x,
                                               float4* __restrict__ xi) {
  int idx = blockIdx.x * 256 + threadIdx.x;
  int b = idx / SPP;
  if (b >= BB) return;
  int p = idx - b * SPP;
  int py = p / SP, px = p - py * SP;
  float4 v = make_float4(0.f, 0.f, 0.f, 0.f);
  if (py >= 2 && py <= 257 && px >= 2 && px <= 257) {
    const float* xb = x + (size_t)b * 3 * HWP + (py - 2) * 256 + (px - 2);
    v = make_float4(xb[0], xb[HWP], xb[2 * HWP], 0.f);
  }
  xi[idx] = v;
}

// ---- pass 2: per-batch tap table: (offx_px, offy_px, w/sum(w), 0) x 128 ----
__global__ __launch_bounds__(128) void stn_tab(const float* __restrict__ theta,
                                               float4* __restrict__ tab) {
  __shared__ float sw[128];
  int b = blockIdx.x, t = threadIdx.x;
  int s = t / 11, u = t - s * 11;                      // dx = lin[t/11], dy = lin[t%11]
  float dx = (float)(s + 1) * (1.0f / 6.0f) - 1.0f;    // linspace(-1,1,13)[1:-1]
  float dy = (float)(u + 1) * (1.0f / 6.0f) - 1.0f;
  float w = (t < 121) ? expf(-8.0f * (dx * dx + dy * dy)) : 0.0f;  // N_SIGMA^2/2 = 8
  sw[t] = w;
  __syncthreads();
  for (int m = 64; m > 0; m >>= 1) {
    if (t < m) sw[t] += sw[t + m];
    __syncthreads();
  }
  float inv = 1.0f / sw[0];
  const float* th = theta + b * 6;
  // pixel-units shift: ((th00*dx + th01*dy) * scale) * 128, scale = 1/99
  float offx = (th[0] * dx + th[1] * dy) * (128.0f / 99.0f);
  float offy = (th[3] * dx + th[4] * dy) * (128.0f / 99.0f);
  if (t >= 121) { offx = 0.f; offy = 0.f; w = 0.f; }
  tab[b * 128 + t] = make_float4(offx, offy, w * inv, 0.f);
}

// ---- pass 3: main — 4 pixels per wave, 16 lanes (= up to 8 taps each) per pixel ----
__global__ __launch_bounds__(256) void stn_main(const float4* __restrict__ xi,
                                                const float4* __restrict__ tab,
                                                const float* __restrict__ theta,
                                                float* __restrict__ out) {
  // 10000 blocks, 16 px/block; bijective XCD swizzle q = 10000/8 = 1250.
  int bid = blockIdx.x;
  int swz = (bid & 7) * 1250 + (bid >> 3);
  int tid = threadIdx.x;
  int sub = tid & 15;

  int pix = swz * 16 + (tid >> 4);          // per-lane pixel id (group = tid>>4)
  // b is block-uniform (10000 % 16 == 0) -> scalarize
  int b = __builtin_amdgcn_readfirstlane(pix / 10000);
  int rem = pix - b * 10000;
  int i = rem / 100;
  int j = rem - i * 100;

  const float* th = theta + b * 6;
  float th00 = th[0], th01 = th[1], th02 = th[2];
  float th10 = th[3], th11 = th[4], th12 = th[5];

  // affine_grid base coords (align_corners=False), unnormalized to pixel units
  float linj = (j + 0.5f) * 0.02f - 1.0f;
  float lini = (i + 0.5f) * 0.02f - 1.0f;
  float bix = (th00 * linj + th01 * lini + th02) * 128.0f + 127.5f;
  float biy = (th10 * linj + th11 * lini + th12) * 128.0f + 127.5f;

  // preload this lane's 8 taps (taps sub+16k; k=7 slots >=121 have w=0)
  const float4* tb = tab + b * 128 + sub;
  float4 t0 = tb[0],  t1 = tb[16], t2 = tb[32], t3 = tb[48];
  float4 t4 = tb[64], t5 = tb[80], t6 = tb[96], t7 = tb[112];

  const float4* xb = xi + (size_t)b * SPP;

  float acc0 = 0.f, acc1 = 0.f, acc2 = 0.f;

#define ROUND(tv)                                                      \
  {                                                                    \
    float ixf = bix + tv.x;                                            \
    float iyf = biy + tv.y;                                            \
    float ix0f = floorf(ixf), iy0f = floorf(iyf);                      \
    float fx = ixf - ix0f, fy = iyf - iy0f;                            \
    int x0 = min(max((int)ix0f + 2, 0), 258);                          \
    int y0 = min(max((int)iy0f + 2, 0), 258);                          \
    float wn = tv.z;                                                   \
    float v1 = wn * fx, u1 = wn - v1;                                  \
    float w00 = u1 - u1 * fy, w10 = u1 * fy;                           \
    float w01 = v1 - v1 * fy, w11 = v1 * fy;                           \
    const float4* r0 = xb + (y0 * SP + x0);                            \
    const float4* r1 = r0 + SP;                                        \
    float4 v00 = r0[0], v01 = r0[1], v10 = r1[0], v11 = r1[1];         \
    acc0 += w00 * v00.x + w01 * v01.x + w10 * v10.x + w11 * v11.x;     \
    acc1 += w00 * v00.y + w01 * v01.y + w10 * v10.y + w11 * v11.y;     \
    acc2 += w00 * v00.z + w01 * v01.z + w10 * v10.z + w11 * v11.z;     \
  }

  ROUND(t0) ROUND(t1) ROUND(t2) ROUND(t3)
  ROUND(t4) ROUND(t5) ROUND(t6) ROUND(t7)
#undef ROUND

  // 16-lane butterfly within each pixel group (xor masks < 16 stay in-group)
#pragma unroll
  for (int m = 1; m < 16; m <<= 1) {
    acc0 += __shfl_xor(acc0, m, 64);
    acc1 += __shfl_xor(acc1, m, 64);
    acc2 += __shfl_xor(acc2, m, 64);
  }

  if (sub == 0) {
    float* ob = out + (size_t)b * 30000 + i * 100 + j;
    ob[0] = acc0;
    ob[10000] = acc1;
    ob[20000] = acc2;
  }
}

// ---- fallback (ws too small): self-contained, bounds-checked, reads x directly ----
__global__ __launch_bounds__(256) void stn_main_fb(const float* __restrict__ x,
                                                   const float* __restrict__ theta,
                                                   float* __restrict__ out) {
  int bid = blockIdx.x;
  int swz = (bid & 7) * 5000 + (bid >> 3);
  int wave = threadIdx.x >> 6;
  int lane = threadIdx.x & 63;
  int pix = swz * 4 + wave;
  int b = pix / 10000;
  int rem = pix - b * 10000;
  int i = rem / 100;
  int j = rem - i * 100;

  const float* th = theta + b * 6;
  float th00 = th[0], th01 = th[1], th02 = th[2];
  float th10 = th[3], th11 = th[4], th12 = th[5];

  float linj = (j + 0.5f) * 0.02f - 1.0f;
  float lini = (i + 0.5f) * 0.02f - 1.0f;
  float bix = (th00 * linj + th01 * lini + th02) * 128.0f + 127.5f;
  float biy = (th10 * linj + th11 * lini + th12) * 128.0f + 127.5f;

  float acc0 = 0.f, acc1 = 0.f, acc2 = 0.f, accw = 0.f;

#pragma unroll
  for (int half = 0; half < 2; ++half) {
    int tap = lane + half * 64;
    if (tap < 121) {
      int s = tap / 11;
      int t = tap - s * 11;
      float dx = (float)(s + 1) * (1.0f / 6.0f) - 1.0f;
      float dy = (float)(t + 1) * (1.0f / 6.0f) - 1.0f;
      float w = __expf(-8.0f * (dx * dx + dy * dy));
      accw += w;
      float offx = (th00 * dx + th01 * dy) * (128.0f / 99.0f);
      float offy = (th10 * dx + th11 * dy) * (128.0f / 99.0f);
      float ixf = bix + offx;
      float iyf = biy + offy;
      float ix0f = floorf(ixf), iy0f = floorf(iyf);
      float fx = ixf - ix0f, fy = iyf - iy0f;
      int ix0 = (int)ix0f, iy0 = (int)iy0f;
      int ix1 = ix0 + 1, iy1 = iy0 + 1;
      float wx0 = ((unsigned)ix0 < 256u) ? (1.0f - fx) : 0.0f;
      float wx1 = ((unsigned)ix1 < 256u) ? fx : 0.0f;
      float wy0 = ((unsigned)iy0 < 256u) ? (1.0f - fy) : 0.0f;
      float wy1 = ((unsigned)iy1 < 256u) ? fy : 0.0f;
      int x0c = min(max(ix0, 0), 255);
      int x1c = min(max(ix1, 0), 255);
      int y0c = min(max(iy0, 0), 255);
      int y1c = min(max(iy1, 0), 255);
      float w00 = w * wy0 * wx0;
      float w01 = w * wy0 * wx1;
      float w10 = w * wy1 * wx0;
      float w11 = w * wy1 * wx1;
      const float* xb0 = x + (size_t)b * 3 * HWP;
      int a00 = y0c * 256 + x0c, a01 = y0c * 256 + x1c;
      int a10 = y1c * 256 + x0c, a11 = y1c * 256 + x1c;
      acc0 += w00 * xb0[a00] + w01 * xb0[a01] + w10 * xb0[a10] + w11 * xb0[a11];
      const float* xb1 = xb0 + HWP;
      acc1 += w00 * xb1[a00] + w01 * xb1[a01] + w10 * xb1[a10] + w11 * xb1[a11];
      const float* xb2 = xb0 + 2 * HWP;
      acc2 += w00 * xb2[a00] + w01 * xb2[a01] + w10 * xb2[a10] + w11 * xb2[a11];
    }
  }

#pragma unroll
  for (int m = 1; m < 64; m <<= 1) {
    acc0 += __shfl_xor(acc0, m, 64);
    acc1 += __shfl_xor(acc1, m, 64);
    acc2 += __shfl_xor(acc2, m, 64);
    accw += __shfl_xor(accw, m, 64);
  }

  if (lane == 0) {
    float inv = 1.0f / accw;
    float* ob = out + (size_t)b * 30000 + i * 100 + j;
    ob[0] = acc0 * inv;
    ob[10000] = acc1 * inv;
    ob[20000] = acc2 * inv;
  }
}

extern "C" void kernel_launch(void* const* d_in, const int* in_sizes, int n_in,
                              void* d_out, int out_size, void* d_ws, size_t ws_size,
                              hipStream_t stream) {
  const float* x = (const float*)d_in[0];      // [16,3,256,256] f32
  const float* theta = (const float*)d_in[1];  // [16,2,3] f32
  float* out = (float*)d_out;                  // [16,3,100,100] f32

  const size_t img_bytes = (size_t)BB * SPP * sizeof(float4);   // 17,305,600
  const size_t tab_bytes = (size_t)BB * 128 * sizeof(float4);   // 32,768
  if (ws_size >= img_bytes + tab_bytes) {
    float4* xi = (float4*)d_ws;
    float4* tab = (float4*)((char*)d_ws + img_bytes);
    stn_pad<<<(BB * SPP + 255) / 256, 256, 0, stream>>>(x, xi);
    stn_tab<<<BB, 128, 0, stream>>>(theta, tab);
    stn_main<<<10000, 256, 0, stream>>>(xi, tab, theta, out);
  } else {
    stn_main_fb<<<40000, 256, 0, stream>>>(x, theta, out);
  }
}

// Round 9
// 98.723 us; speedup vs baseline: 1.3436x; 1.2308x over previous
//
#include <hip/hip_runtime.h>
#include <hip/hip_fp16.h>

// SpatialTransformerNetwork: B=16,C=3,H=W=256 -> out [16,3,100,100]
// 121 Gaussian taps (11x11), bilinear grid_sample, zeros padding, align_corners=False.
//
// R5 (vmem-latency/L1-return bound per R4: VALUBusy 39%, dur stuck at 58us):
//  - image repacked to f16x4 per pixel (ch0,ch1,ch2,pad = 8B) in 260x260 padded
//    plane: both x-corners of a tap fit ONE dwordx4 load -> 2 loads/tap (was 4),
//    bytes through L1 halved.
//  - 4-tap chunks, phase-split: issue 8 loads, then do math -> 8 loads in
//    flight per wave (latency hiding without more occupancy).
//  - bilinear lerp in packed half2 (v_pk_fma_f16), accumulate f32.
//  - keep: 16 lanes/pixel, 4 px/wave, per-batch tap LUT, med3 clamps into
//    2-wide zero border, 16-lane butterfly reduction.

#define BB 16
#define HWP 65536      // 256*256
#define SP 260         // padded dim (2 zeros on each side)
#define SPP (SP * SP)  // 67600 pixels per padded batch plane
#define ROWB (SP * 8)  // padded row bytes (2080)

typedef uint4 __attribute__((aligned(8))) uint4_a8;  // pixel stride is 8B

// ---- pass 1: pad + channel-pack to f16x4: x[B,3,256,256] -> xi[B,260,260] (8B/px) ----
__global__ __launch_bounds__(256) void stn_pad(const float* __restrict__ x,
                                               uint2* __restrict__ xi) {
  int idx = blockIdx.x * 256 + threadIdx.x;   // 0 .. 16*67600-1
  int b = idx / SPP;
  if (b >= BB) return;
  int p = idx - b * SPP;
  int py = p / SP, px = p - py * SP;
  float v0 = 0.f, v1 = 0.f, v2 = 0.f;
  if (py >= 2 && py <= 257 && px >= 2 && px <= 257) {
    const float* xb = x + (size_t)b * 3 * HWP + (py - 2) * 256 + (px - 2);
    v0 = xb[0]; v1 = xb[HWP]; v2 = xb[2 * HWP];
  }
  __half2 p01 = __floats2half2_rn(v0, v1);
  __half2 p2 = __floats2half2_rn(v2, 0.f);
  xi[idx] = make_uint2(__builtin_bit_cast(unsigned, p01), __builtin_bit_cast(unsigned, p2));
}

// ---- pass 2: per-batch tap table: (offx_px, offy_px, w/sum(w), 0) x 128 ----
__global__ __launch_bounds__(128) void stn_tab(const float* __restrict__ theta,
                                               float4* __restrict__ tab) {
  __shared__ float sw[128];
  int b = blockIdx.x, t = threadIdx.x;
  int s = t / 11, u = t - s * 11;                      // dx = lin[t/11], dy = lin[t%11]
  float dx = (float)(s + 1) * (1.0f / 6.0f) - 1.0f;    // linspace(-1,1,13)[1:-1]
  float dy = (float)(u + 1) * (1.0f / 6.0f) - 1.0f;
  float w = (t < 121) ? expf(-8.0f * (dx * dx + dy * dy)) : 0.0f;  // N_SIGMA^2/2 = 8
  sw[t] = w;
  __syncthreads();
  for (int m = 64; m > 0; m >>= 1) {
    if (t < m) sw[t] += sw[t + m];
    __syncthreads();
  }
  float inv = 1.0f / sw[0];
  const float* th = theta + b * 6;
  // pixel-units shift: ((th00*dx + th01*dy) * scale) * 128, scale = 1/99
  float offx = (th[0] * dx + th[1] * dy) * (128.0f / 99.0f);
  float offy = (th[3] * dx + th[4] * dy) * (128.0f / 99.0f);
  if (t >= 121) { offx = 0.f; offy = 0.f; w = 0.f; }
  tab[b * 128 + t] = make_float4(offx, offy, w * inv, 0.f);
}

// ---- pass 3: main — 4 px/wave, 16 lanes/px, 2 chunks x 4 taps, phase-split ----
__global__ __launch_bounds__(256) void stn_main(const uint2* __restrict__ xi,
                                                const float4* __restrict__ tab,
                                                const float* __restrict__ theta,
                                                float* __restrict__ out) {
  // 10000 blocks, 16 px/block; bijective XCD swizzle q = 10000/8 = 1250.
  int bid = blockIdx.x;
  int swz = (bid & 7) * 1250 + (bid >> 3);
  int tid = threadIdx.x;
  int sub = tid & 15;

  int pix = swz * 16 + (tid >> 4);
  int b = __builtin_amdgcn_readfirstlane(pix / 10000);   // block-uniform
  int rem = pix - b * 10000;
  int i = rem / 100;
  int j = rem - i * 100;

  const float* th = theta + b * 6;
  float th00 = th[0], th01 = th[1], th02 = th[2];
  float th10 = th[3], th11 = th[4], th12 = th[5];

  // affine_grid base coords (align_corners=False), unnormalized to pixel units
  float linj = (j + 0.5f) * 0.02f - 1.0f;
  float lini = (i + 0.5f) * 0.02f - 1.0f;
  float bix = (th00 * linj + th01 * lini + th02) * 128.0f + 127.5f;
  float biy = (th10 * linj + th11 * lini + th12) * 128.0f + 127.5f;

  const float4* tb = tab + b * 128 + sub;      // this lane's taps: tb[16*k]
  const char* base = (const char*)(xi + (size_t)b * SPP);

  float acc0 = 0.f, acc1 = 0.f, acc2 = 0.f;

#pragma unroll
  for (int c = 0; c < 2; ++c) {
    uint4 dA[4], dB[4];
    float wa[4], wb[4], fyv[4];
#pragma unroll
    for (int k = 0; k < 4; ++k) {
      float4 tv = tb[(c * 4 + k) * 16];
      float ixf = bix + tv.x;
      float iyf = biy + tv.y;
      float xf0 = floorf(ixf), yf0 = floorf(iyf);
      float fx = ixf - xf0, fy = iyf - yf0;
      // clamp into padded coords; OOB lands in the zero border (x1=x0+1 <= 259)
      int x0 = min(max((int)xf0 + 2, 0), 258);
      int y0 = min(max((int)yf0 + 2, 0), 258);
      const char* p = base + (y0 * ROWB + x0 * 8);
      dA[k] = *(const uint4_a8*)p;            // row y0: [x0: c01,c2p | x1: c01,c2p]
      dB[k] = *(const uint4_a8*)(p + ROWB);   // row y1
      float vb = tv.z * fx;
      wa[k] = tv.z - vb;                   // wn*(1-fx)
      wb[k] = vb;                          // wn*fx
      fyv[k] = fy;
    }
#pragma unroll
    for (int k = 0; k < 4; ++k) {
      __half2 wa2 = __float2half2_rn(wa[k]);
      __half2 wb2 = __float2half2_rn(wb[k]);
      __half2 wy0 = __float2half2_rn(1.0f - fyv[k]);
      __half2 wy1 = __float2half2_rn(fyv[k]);
      __half2 a0 = __builtin_bit_cast(__half2, dA[k].x);  // y0,x0 ch01
      __half2 a1 = __builtin_bit_cast(__half2, dA[k].y);  // y0,x0 ch2_
      __half2 a2 = __builtin_bit_cast(__half2, dA[k].z);  // y0,x1 ch01
      __half2 a3 = __builtin_bit_cast(__half2, dA[k].w);  // y0,x1 ch2_
      __half2 b0 = __builtin_bit_cast(__half2, dB[k].x);
      __half2 b1 = __builtin_bit_cast(__half2, dB[k].y);
      __half2 b2 = __builtin_bit_cast(__half2, dB[k].z);
      __half2 b3 = __builtin_bit_cast(__half2, dB[k].w);
      __half2 r0c01 = __hfma2(a2, wb2, __hmul2(a0, wa2));  // horizontal lerp, row y0
      __half2 r0c2  = __hfma2(a3, wb2, __hmul2(a1, wa2));
      __half2 r1c01 = __hfma2(b2, wb2, __hmul2(b0, wa2));  // row y1
      __half2 r1c2  = __hfma2(b3, wb2, __hmul2(b1, wa2));
      __half2 o01 = __hfma2(r1c01, wy1, __hmul2(r0c01, wy0));  // vertical lerp
      __half2 o2  = __hfma2(r1c2,  wy1, __hmul2(r0c2,  wy0));
      acc0 += __low2float(o01);
      acc1 += __high2float(o01);
      acc2 += __low2float(o2);
    }
  }

  // 16-lane butterfly within each pixel group (xor masks < 16 stay in-group)
#pragma unroll
  for (int m = 1; m < 16; m <<= 1) {
    acc0 += __shfl_xor(acc0, m, 64);
    acc1 += __shfl_xor(acc1, m, 64);
    acc2 += __shfl_xor(acc2, m, 64);
  }

  if (sub == 0) {
    float* ob = out + (size_t)b * 30000 + i * 100 + j;
    ob[0] = acc0;
    ob[10000] = acc1;
    ob[20000] = acc2;
  }
}

// ---- fallback (ws too small): self-contained, bounds-checked, reads x directly ----
__global__ __launch_bounds__(256) void stn_main_fb(const float* __restrict__ x,
                                                   const float* __restrict__ theta,
                                                   float* __restrict__ out) {
  int bid = blockIdx.x;
  int swz = (bid & 7) * 5000 + (bid >> 3);
  int wave = threadIdx.x >> 6;
  int lane = threadIdx.x & 63;
  int pix = swz * 4 + wave;
  int b = pix / 10000;
  int rem = pix - b * 10000;
  int i = rem / 100;
  int j = rem - i * 100;

  const float* th = theta + b * 6;
  float th00 = th[0], th01 = th[1], th02 = th[2];
  float th10 = th[3], th11 = th[4], th12 = th[5];

  float linj = (j + 0.5f) * 0.02f - 1.0f;
  float lini = (i + 0.5f) * 0.02f - 1.0f;
  float bix = (th00 * linj + th01 * lini + th02) * 128.0f + 127.5f;
  float biy = (th10 * linj + th11 * lini + th12) * 128.0f + 127.5f;

  float acc0 = 0.f, acc1 = 0.f, acc2 = 0.f, accw = 0.f;

#pragma unroll
  for (int half = 0; half < 2; ++half) {
    int tap = lane + half * 64;
    if (tap < 121) {
      int s = tap / 11;
      int t = tap - s * 11;
      float dx = (float)(s + 1) * (1.0f / 6.0f) - 1.0f;
      float dy = (float)(t + 1) * (1.0f / 6.0f) - 1.0f;
      float w = __expf(-8.0f * (dx * dx + dy * dy));
      accw += w;
      float offx = (th00 * dx + th01 * dy) * (128.0f / 99.0f);
      float offy = (th10 * dx + th11 * dy) * (128.0f / 99.0f);
      float ixf = bix + offx;
      float iyf = biy + offy;
      float ix0f = floorf(ixf), iy0f = floorf(iyf);
      float fx = ixf - ix0f, fy = iyf - iy0f;
      int ix0 = (int)ix0f, iy0 = (int)iy0f;
      int ix1 = ix0 + 1, iy1 = iy0 + 1;
      float wx0 = ((unsigned)ix0 < 256u) ? (1.0f - fx) : 0.0f;
      float wx1 = ((unsigned)ix1 < 256u) ? fx : 0.0f;
      float wy0 = ((unsigned)iy0 < 256u) ? (1.0f - fy) : 0.0f;
      float wy1 = ((unsigned)iy1 < 256u) ? fy : 0.0f;
      int x0c = min(max(ix0, 0), 255);
      int x1c = min(max(ix1, 0), 255);
      int y0c = min(max(iy0, 0), 255);
      int y1c = min(max(iy1, 0), 255);
      float w00 = w * wy0 * wx0;
      float w01 = w * wy0 * wx1;
      float w10 = w * wy1 * wx0;
      float w11 = w * wy1 * wx1;
      const float* xb0 = x + (size_t)b * 3 * HWP;
      int a00 = y0c * 256 + x0c, a01 = y0c * 256 + x1c;
      int a10 = y1c * 256 + x0c, a11 = y1c * 256 + x1c;
      acc0 += w00 * xb0[a00] + w01 * xb0[a01] + w10 * xb0[a10] + w11 * xb0[a11];
      const float* xb1 = xb0 + HWP;
      acc1 += w00 * xb1[a00] + w01 * xb1[a01] + w10 * xb1[a10] + w11 * xb1[a11];
      const float* xb2 = xb0 + 2 * HWP;
      acc2 += w00 * xb2[a00] + w01 * xb2[a01] + w10 * xb2[a10] + w11 * xb2[a11];
    }
  }

#pragma unroll
  for (int m = 1; m < 64; m <<= 1) {
    acc0 += __shfl_xor(acc0, m, 64);
    acc1 += __shfl_xor(acc1, m, 64);
    acc2 += __shfl_xor(acc2, m, 64);
    accw += __shfl_xor(accw, m, 64);
  }

  if (lane == 0) {
    float inv = 1.0f / accw;
    float* ob = out + (size_t)b * 30000 + i * 100 + j;
    ob[0] = acc0 * inv;
    ob[10000] = acc1 * inv;
    ob[20000] = acc2 * inv;
  }
}

extern "C" void kernel_launch(void* const* d_in, const int* in_sizes, int n_in,
                              void* d_out, int out_size, void* d_ws, size_t ws_size,
                              hipStream_t stream) {
  const float* x = (const float*)d_in[0];      // [16,3,256,256] f32
  const float* theta = (const float*)d_in[1];  // [16,2,3] f32
  float* out = (float*)d_out;                  // [16,3,100,100] f32

  const size_t img_bytes = (size_t)BB * SPP * sizeof(uint2);    // 8,652,800
  const size_t tab_bytes = (size_t)BB * 128 * sizeof(float4);   // 32,768
  if (ws_size >= img_bytes + tab_bytes) {
    uint2* xi = (uint2*)d_ws;
    float4* tab = (float4*)((char*)d_ws + img_bytes);
    stn_pad<<<(BB * SPP + 255) / 256, 256, 0, stream>>>(x, xi);
    stn_tab<<<BB, 128, 0, stream>>>(theta, tab);
    stn_main<<<10000, 256, 0, stream>>>(xi, tab, theta, out);
  } else {
    stn_main_fb<<<40000, 256, 0, stream>>>(x, theta, out);
  }
}